// Round 7
// baseline (149.802 us; speedup 1.0000x reference)
//
#include <hip/hip_runtime.h>

typedef float v2f __attribute__((ext_vector_type(2)));

#define NN 768
#define NPAIRS ((NN * (NN - 1)) / 2)   // 294528
#define MARGIN_F 0.01f
#define CHUNK 128                      // k-nodes per thread (768/6)
#define NCHUNK 6

// Pre-pass: SoA node data in d_ws: xs[768] | ys[768] | zs[768] (z = x^2+y^2).
// SoA so the wave-uniform k-loop loads return ADJACENT node pairs -> packed
// VOP3P sources without any repacking.
__global__ __launch_bounds__(256) void gg_pre(const float* __restrict__ pos,
                                              float* __restrict__ ws) {
    int i = blockIdx.x * blockDim.x + threadIdx.x;
    if (i < NN) {
        float x = pos[2 * i], y = pos[2 * i + 1];
        ws[i]            = x;
        ws[NN + i]       = y;
        ws[2 * NN + i]   = fmaf(x, x, y * y);
    }
}

__global__ __launch_bounds__(256) void gg_main(const float* __restrict__ pos,
                                               const float* __restrict__ ws,
                                               float* __restrict__ out,
                                               float inv_total) {
    int p = blockIdx.x * blockDim.x + threadIdx.x;
    int kbase = blockIdx.y * CHUNK;
    v2f acc2 = {0.0f, 0.0f};

    if (p < NPAIRS) {
        // ---- unrank linear pair index p -> (i, j), i < j ----
        const float A = 2.0f * NN - 1.0f;          // 1535
        float disc = A * A - 8.0f * (float)p;      // integers < 2^24, exact in f32
        int i = (int)((A - __builtin_amdgcn_sqrtf(disc)) * 0.5f);
        if (i < 0) i = 0;
        if (i > NN - 2) i = NN - 2;
        while (((i + 1) * (2 * NN - 1 - (i + 1))) / 2 <= p) ++i;
        while ((i * (2 * NN - 1 - i)) / 2 > p) --i;
        int off = (i * (2 * NN - 1 - i)) / 2;
        int j = i + 1 + (p - off);

        // ---- per-pair: midpoint, radius, quadratic-form constants ----
        float xix = pos[2 * i], xiy = pos[2 * i + 1];
        float xjx = pos[2 * j], xjy = pos[2 * j + 1];
        float mx = 0.5f * (xix + xjx);
        float my = 0.5f * (xiy + xjy);
        float ddx = xix - xjx, ddy = xiy - xjy;
        float r  = 0.5f * __builtin_amdgcn_sqrtf(fmaf(ddx, ddx, ddy * ddy)) + MARGIN_F;

        v2f cx2 = {-2.0f * mx, -2.0f * mx};
        v2f cy2 = {-2.0f * my, -2.0f * my};
        v2f cc2;  cc2.x = fmaf(mx, mx, my * my);  cc2.y = cc2.x;   // |mid|^2
        v2f rv  = {r, r};
        v2f neg1 = {-1.0f, -1.0f};
        v2f zero = {0.0f, 0.0f};

        // wave-uniform SoA pair pointers (8B-aligned: kbase is even)
        const v2f* xs2 = (const v2f*)(ws + kbase);
        const v2f* ys2 = (const v2f*)(ws + NN + kbase);
        const v2f* zs2 = (const v2f*)(ws + 2 * NN + kbase);

        // ---- inner loop, 2 nodes/iter, packed f32 (v_pk_fma/add) ----
        // dist^2 = z_k - 2 x_k.mid + |mid|^2 ; t = max(r - d, 0); acc += t^2
        #pragma unroll 8
        for (int t = 0; t < CHUNK / 2; ++t) {
            v2f xv = xs2[t];
            v2f yv = ys2[t];
            v2f zv = zs2[t];
            v2f c  = zv + cc2;                                  // v_pk_add_f32
            c      = __builtin_elementwise_fma(yv, cy2, c);     // v_pk_fma_f32
            v2f d2 = __builtin_elementwise_fma(xv, cx2, c);     // v_pk_fma_f32
            v2f d;
            d.x = __builtin_amdgcn_sqrtf(d2.x);                 // v_sqrt_f32 x2
            d.y = __builtin_amdgcn_sqrtf(d2.y);
            v2f tt = __builtin_elementwise_fma(d, neg1, rv);    // r - d (pk_fma)
            tt = __builtin_elementwise_max(tt, zero);           // v_max_f32 x2 (or pk)
            acc2 = __builtin_elementwise_fma(tt, tt, acc2);     // v_pk_fma_f32
        }
    }

    float acc = acc2.x + acc2.y;

    // ---- wave reduce (64 lanes) ----
    for (int o = 32; o > 0; o >>= 1) acc += __shfl_down(acc, o);

    __shared__ float wsum[4];
    int lane = threadIdx.x & 63;
    int wid  = threadIdx.x >> 6;
    if (lane == 0) wsum[wid] = acc;
    __syncthreads();
    if (threadIdx.x == 0) {
        float s = (wsum[0] + wsum[1]) + (wsum[2] + wsum[3]);
        atomicAdd(out, s * inv_total);
    }
}

extern "C" void kernel_launch(void* const* d_in, const int* in_sizes, int n_in,
                              void* d_out, int out_size, void* d_ws, size_t ws_size,
                              hipStream_t stream) {
    const float* pos = (const float*)d_in[0];
    float* out = (float*)d_out;
    float* ws  = (float*)d_ws;

    // d_out / d_ws re-poisoned 0xAA before every launch
    hipMemsetAsync(out, 0, sizeof(float), stream);
    gg_pre<<<NCHUNK, 256, 0, stream>>>(pos, ws);

    double total = (double)NN * (double)NPAIRS;
    float inv_total = (float)(1.0 / total);

    dim3 grid((NPAIRS + 255) / 256, NCHUNK);     // 1151 x 6 blocks
    gg_main<<<grid, 256, 0, stream>>>(pos, ws, out, inv_total);
}